// Round 2
// baseline (535.231 us; speedup 1.0000x reference)
//
#include <hip/hip_runtime.h>
#include <hip/hip_fp16.h>
#include <hip/hip_cooperative_groups.h>
#include <stdint.h>
#include <string.h>

// LightGCN propagation — R16: cooperative mega-fusion (3 nodes total).
//  K1: single-round LDS-staged counting sort (293 edge blocks, NBKT=512,
//      SCAP=16) + parallel flat writeout + mark + cvt ride-alongs.
//  MEGA (cooperative, 512 blocks x 512 thr, 2 grid syncs):
//    phase A: per-bucket ELL build in LDS -> cnt-pruned writeout -> layer-1
//             spmm from LDS; + acc0 / mask-expand / mask-copy ride-alongs.
//    sync -> phase B: layer-2 spmm (mask2 rows, grid-strided) + acc1.
//    sync -> phase C: slot-form layer 3 fused with the batched dot
//             (user/item pair in adjacent 16-lane groups, shfl_xor(16)).
//  Removes 3 kernel-node boundaries (~10 us each) + the dot kernel.

#define NUM_USERS 100000
#define NUM_ITEMS 50000
#define N_NODES   150000
#define DIM       64
#define N_EDGES   1200000
#define ND        (N_NODES * DIM)
#define NB        4096
#define NSAMP     (2 * NB)

#define ELL_W     24
#define NBKT      512               // buckets == mega grid
#define RPB       293               // rows per bucket (512*293 = 150016)
#define NROWS_PAD (NBKT * RPB)
#define BCAP      2688              // records per bucket (mean 2344, +7s)
#define SCAP      16                // K1 LDS staging records per bucket
#define OVF_CAP   512

#define K1_THREADS     1024
#define K1_EDGE_BLOCKS 293          // 293*1024*4 = 1,200,128 >= N_EDGES
#define K1_MARK_BLOCKS 8
#define K1_CVT_BLOCKS  128

#define MEGA_THREADS   512
#define MEGA_BLOCKS    512          // == NBKT; 2 blocks/CU guaranteed co-resident

namespace cg = cooperative_groups;

// ---- fp16 pack/unpack helpers (compute in fp32) ---------------------------
__device__ __forceinline__ int h2i(__half2 h) { int r; memcpy(&r, &h, 4); return r; }
__device__ __forceinline__ __half2 i2h(int i) { __half2 h; memcpy(&h, &i, 4); return h; }

__device__ __forceinline__ float4 loadh4(const __half* p) {
    int2 v = *(const int2*)p;
    float2 a = __half22float2(i2h(v.x));
    float2 b = __half22float2(i2h(v.y));
    return make_float4(a.x, a.y, b.x, b.y);
}
__device__ __forceinline__ void storeh4(__half* p, float4 v) {
    int2 o;
    o.x = h2i(__floats2half2_rn(v.x, v.y));
    o.y = h2i(__floats2half2_rn(v.z, v.w));
    *(int2*)p = o;
}
__device__ __forceinline__ float4 f4fma(float v, float4 x, float4 a) {
    a.x += v * x.x; a.y += v * x.y; a.z += v * x.z; a.w += v * x.w;
    return a;
}

// ---------------------------------------------------------------------------
// K1: single-round LDS-staged counting sort + parallel writeout
//     + mark + cvt ride-alongs
// ---------------------------------------------------------------------------
__global__ __launch_bounds__(K1_THREADS)
void k1_kernel(const int* __restrict__ erow,
               const int* __restrict__ ecol,
               const float* __restrict__ evalv,
               const int* __restrict__ users,
               const int* __restrict__ items,
               const float* __restrict__ ue,
               const float* __restrict__ ie,
               int* __restrict__ gtails,
               int2* __restrict__ barr,
               int4* __restrict__ ovf,
               int* __restrict__ ovf_cnt,
               unsigned char* __restrict__ mask3,
               __half* __restrict__ xh) {
    __shared__ int2 stage[NBKT * SCAP];   // 64 KB
    __shared__ int  scnt[NBKT];           // 2 KB
    __shared__ int  gpos[NBKT];           // 2 KB
    if (blockIdx.x < K1_EDGE_BLOCKS) {
        for (int k = threadIdx.x; k < NBKT; k += K1_THREADS) scnt[k] = 0;
        __syncthreads();
        int base = ((int)blockIdx.x * K1_THREADS + (int)threadIdx.x) * 4;
        if (base < N_EDGES) {            // N_EDGES % 4 == 0 -> all 4 valid
            int4   r4 = *(const int4*)(erow + base);
            int4   c4 = *(const int4*)(ecol + base);
            float4 v4 = *(const float4*)(evalv + base);
            int   rr[4] = {r4.x, r4.y, r4.z, r4.w};
            int   cc[4] = {c4.x, c4.y, c4.z, c4.w};
            float vv[4] = {v4.x, v4.y, v4.z, v4.w};
            #pragma unroll
            for (int u = 0; u < 4; ++u) {
                int b    = rr[u] / RPB;
                int rloc = rr[u] - b * RPB;
                int2 rec = make_int2(cc[u] | (rloc << 18), __float_as_int(vv[u]));
                int s = atomicAdd(&scnt[b], 1);
                if (s < SCAP) {
                    stage[(b << 4) + s] = rec;
                } else {
                    // rare (Poisson lambda=8 vs cap 16): spill straight to global
                    int gp = atomicAdd(&gtails[b], 1);
                    if (gp < BCAP) barr[(size_t)b * BCAP + gp] = rec;
                    else { int q = atomicAdd(ovf_cnt, 1);
                           if (q < OVF_CAP)
                               ovf[q] = make_int4(rr[u], cc[u], __float_as_int(vv[u]), 0); }
                }
            }
        }
        __syncthreads();
        // grab per-bucket global ranges (one atomic per bucket)
        for (int b = threadIdx.x; b < NBKT; b += K1_THREADS) {
            int c = scnt[b];
            c = c < SCAP ? c : SCAP;     // clamp: spilled records already placed
            scnt[b] = c;
            gpos[b] = (c > 0) ? atomicAdd(&gtails[b], c) : 0;
        }
        __syncthreads();
        // flat parallel writeout over (bucket, record) pairs — all 1024 threads
        for (int idx = threadIdx.x; idx < NBKT * SCAP; idx += K1_THREADS) {
            int b = idx >> 4;
            int i = idx & 15;
            if (i < scnt[b]) {
                int2 rc = stage[idx];
                int gp = gpos[b] + i;
                if (gp < BCAP) barr[(size_t)b * BCAP + gp] = rc;
                else { int q = atomicAdd(ovf_cnt, 1);
                       if (q < OVF_CAP)
                           ovf[q] = make_int4(b * RPB + (rc.x >> 18),
                                              rc.x & 0x3FFFF, rc.y, 0); }
            }
        }
    } else if (blockIdx.x < K1_EDGE_BLOCKS + K1_MARK_BLOCKS) {
        int i = ((int)blockIdx.x - K1_EDGE_BLOCKS) * K1_THREADS + (int)threadIdx.x;
        if (i < NB)         mask3[users[i]] = 1;
        else if (i < NSAMP) mask3[NUM_USERS + items[i - NB]] = 1;
    } else {
        const int n4  = ND / 4;
        const int nu4 = NUM_USERS * DIM / 4;
        int i = ((int)blockIdx.x - K1_EDGE_BLOCKS - K1_MARK_BLOCKS) * K1_THREADS
                + (int)threadIdx.x;
        const int stride = K1_CVT_BLOCKS * K1_THREADS;
        int2* xh4 = (int2*)xh;
        for (; i < n4; i += stride) {
            float4 v = (i < nu4) ? ((const float4*)ue)[i]
                                 : ((const float4*)ie)[i - nu4];
            int2 o;
            o.x = h2i(__floats2half2_rn(v.x, v.y));
            o.y = h2i(__floats2half2_rn(v.z, v.w));
            xh4[i] = o;
        }
    }
}

// ---------------------------------------------------------------------------
// MEGA: ELL build + layer-1 | sync | layer-2 + acc1 | sync | layer-3 + dot
// ---------------------------------------------------------------------------
__global__ __launch_bounds__(MEGA_THREADS, 4)
void mega_kernel(const int* __restrict__ erow,
                 const int* __restrict__ ecol,
                 const int* __restrict__ gtails,
                 const int2* __restrict__ barr,
                 const __half* __restrict__ xh,
                 const float* __restrict__ ue,
                 const float* __restrict__ ie,
                 int* __restrict__ counts,
                 int2* __restrict__ ell,
                 int4* __restrict__ ovf,
                 int* __restrict__ ovf_cnt,
                 const unsigned char* __restrict__ mask3,
                 unsigned char* __restrict__ mask2,
                 const int* __restrict__ users,
                 const int* __restrict__ items,
                 float* __restrict__ acc_small,
                 __half* __restrict__ emb_a,
                 __half* __restrict__ emb_b,
                 float* __restrict__ out) {
    __shared__ __align__(16) int2 lell[RPB * ELL_W];   // 56.3 KB
    __shared__ int lcnt[RPB];
    cg::grid_group grid = cg::this_grid();
    const int group = threadIdx.x >> 4;   // 0..31
    const int t     = threadIdx.x & 15;
    const int gid   = (int)blockIdx.x * MEGA_THREADS + (int)threadIdx.x;
    const int gsz   = MEGA_BLOCKS * MEGA_THREADS;      // 262144

    // ================= phase A: bucket (one per block) =====================
    {
        const int bkt   = blockIdx.x;
        const int rbase = bkt * RPB;
        for (int k = threadIdx.x; k < RPB; k += MEGA_THREADS) lcnt[k] = 0;
        __syncthreads();
        int n = gtails[bkt];
        n = n < BCAP ? n : BCAP;
        for (int e = threadIdx.x; e < n; e += MEGA_THREADS) {
            int2 rec = barr[(size_t)bkt * BCAP + e];
            int col  = rec.x & 0x3FFFF;
            int rloc = rec.x >> 18;
            int slot = atomicAdd(&lcnt[rloc], 1);
            if (slot < ELL_W)
                lell[rloc * ELL_W + slot] = make_int2(col, rec.y);
            else { int q = atomicAdd(ovf_cnt, 1);
                   if (q < OVF_CAP) ovf[q] = make_int4(rbase + rloc, col, rec.y, 0); }
        }
        __syncthreads();
        // cnt-pruned ELL writeout (rows are 192B line-aligned)
        {
            int4* g4 = (int4*)(ell + (size_t)rbase * ELL_W);
            const int4* l4 = (const int4*)lell;
            const int PPR = ELL_W / 2;   // 12 int4 pairs per row
            for (int idx = threadIdx.x; idx < RPB * PPR; idx += MEGA_THREADS) {
                int row = idx / PPR;
                int pr  = idx - row * PPR;
                int c = lcnt[row]; c = c < ELL_W ? c : ELL_W;
                if (pr * 2 < c) g4[idx] = l4[idx];
            }
            for (int k = threadIdx.x; k < RPB; k += MEGA_THREADS)
                counts[rbase + k] = lcnt[k];
        }
        // layer-1 spmm reading ELL from LDS
        int novf = *ovf_cnt;
        novf = novf < OVF_CAP ? novf : OVF_CAP;
        for (int k = 0; k < 10; ++k) {               // 32 groups x 10 = 320 >= 293
            int rloc = group + 32 * k;
            if (rloc >= RPB) break;
            int row = rbase + rloc;
            if (row >= N_NODES) continue;
            int cnt = lcnt[rloc];
            cnt = cnt < ELL_W ? cnt : ELL_W;
            const int2* ep = &lell[rloc * ELL_W];
            float4 a0 = {0,0,0,0}, a1 = {0,0,0,0}, a2 = {0,0,0,0}, a3 = {0,0,0,0};
            int j = 0;
            for (; j + 4 <= cnt; j += 4) {
                int4 cv0 = *(const int4*)(ep + j);
                int4 cv1 = *(const int4*)(ep + j + 2);
                float4 x0 = loadh4(xh + (size_t)cv0.x * DIM + t * 4);
                float4 x1 = loadh4(xh + (size_t)cv0.z * DIM + t * 4);
                float4 x2 = loadh4(xh + (size_t)cv1.x * DIM + t * 4);
                float4 x3 = loadh4(xh + (size_t)cv1.z * DIM + t * 4);
                a0 = f4fma(__int_as_float(cv0.y), x0, a0);
                a1 = f4fma(__int_as_float(cv0.w), x1, a1);
                a2 = f4fma(__int_as_float(cv1.y), x2, a2);
                a3 = f4fma(__int_as_float(cv1.w), x3, a3);
            }
            for (; j + 2 <= cnt; j += 2) {
                int4 cv = *(const int4*)(ep + j);
                float4 x0 = loadh4(xh + (size_t)cv.x * DIM + t * 4);
                float4 x1 = loadh4(xh + (size_t)cv.z * DIM + t * 4);
                a0 = f4fma(__int_as_float(cv.y), x0, a0);
                a1 = f4fma(__int_as_float(cv.w), x1, a1);
            }
            if (j < cnt) {
                int2 cv = ep[j];
                float4 xv = loadh4(xh + (size_t)cv.x * DIM + t * 4);
                a0 = f4fma(__int_as_float(cv.y), xv, a0);
            }
            for (int q = 0; q < novf; ++q) {
                int4 o = ovf[q];
                if (o.x == row) {
                    float4 xv = loadh4(xh + (size_t)o.y * DIM + t * 4);
                    a0 = f4fma(__int_as_float(o.z), xv, a0);
                }
            }
            float4 self = loadh4(xh + (size_t)row * DIM + t * 4);
            float4 r;
            r.x = 0.2f * self.x + 0.8f * ((a0.x + a1.x) + (a2.x + a3.x));
            r.y = 0.2f * self.y + 0.8f * ((a0.y + a1.y) + (a2.y + a3.y));
            r.z = 0.2f * self.z + 0.8f * ((a0.z + a1.z) + (a2.z + a3.z));
            r.w = 0.2f * self.w + 0.8f * ((a0.w + a1.w) + (a2.w + a3.w));
            storeh4(emb_a + (size_t)row * DIM + t * 4, r);
        }
    }
    // ---- ride-alongs: acc0, mask expand, mask copy ----
    for (int i = gid; i < NSAMP * 16; i += gsz) {
        int s  = i >> 4;
        int tt = i & 15;
        int node = (s < NB) ? users[s] : (NUM_USERS + items[s - NB]);
        const float* p = (node < NUM_USERS) ? ue + (size_t)node * DIM
                                            : ie + (size_t)(node - NUM_USERS) * DIM;
        *(float4*)(acc_small + (size_t)s * DIM + tt * 4) = *(const float4*)(p + tt * 4);
    }
    for (int i = gid; i < N_EDGES; i += gsz)
        if (mask3[erow[i]]) mask2[ecol[i]] = 1;
    for (int i = gid; i < N_NODES; i += gsz)
        if (mask3[i]) mask2[i] = 1;

    __threadfence();
    grid.sync();

    // ================= phase B: layer-2 spmm (mask2) + acc1 ================
    {
        const int ggrp = gid >> 4;                 // 16384 groups
        const int gstep = gsz >> 4;
        int novf = *ovf_cnt;
        novf = novf < OVF_CAP ? novf : OVF_CAP;
        for (int row = ggrp; row < N_NODES; row += gstep) {
            if (!mask2[row]) continue;
            int cnt = counts[row];
            cnt = cnt < ELL_W ? cnt : ELL_W;
            const int2* ep = ell + (size_t)row * ELL_W;
            float4 a0 = {0,0,0,0}, a1 = {0,0,0,0}, a2 = {0,0,0,0}, a3 = {0,0,0,0};
            int j = 0;
            for (; j + 4 <= cnt; j += 4) {
                int4 cv0 = *(const int4*)(ep + j);
                int4 cv1 = *(const int4*)(ep + j + 2);
                float4 x0 = loadh4(emb_a + (size_t)cv0.x * DIM + t * 4);
                float4 x1 = loadh4(emb_a + (size_t)cv0.z * DIM + t * 4);
                float4 x2 = loadh4(emb_a + (size_t)cv1.x * DIM + t * 4);
                float4 x3 = loadh4(emb_a + (size_t)cv1.z * DIM + t * 4);
                a0 = f4fma(__int_as_float(cv0.y), x0, a0);
                a1 = f4fma(__int_as_float(cv0.w), x1, a1);
                a2 = f4fma(__int_as_float(cv1.y), x2, a2);
                a3 = f4fma(__int_as_float(cv1.w), x3, a3);
            }
            for (; j + 2 <= cnt; j += 2) {
                int4 cv = *(const int4*)(ep + j);
                float4 x0 = loadh4(emb_a + (size_t)cv.x * DIM + t * 4);
                float4 x1 = loadh4(emb_a + (size_t)cv.z * DIM + t * 4);
                a0 = f4fma(__int_as_float(cv.y), x0, a0);
                a1 = f4fma(__int_as_float(cv.w), x1, a1);
            }
            if (j < cnt) {
                int2 cv = ep[j];
                float4 xv = loadh4(emb_a + (size_t)cv.x * DIM + t * 4);
                a0 = f4fma(__int_as_float(cv.y), xv, a0);
            }
            for (int q = 0; q < novf; ++q) {
                int4 o = ovf[q];
                if (o.x == row) {
                    float4 xv = loadh4(emb_a + (size_t)o.y * DIM + t * 4);
                    a0 = f4fma(__int_as_float(o.z), xv, a0);
                }
            }
            float4 self = loadh4(emb_a + (size_t)row * DIM + t * 4);
            float4 r;
            r.x = 0.2f * self.x + 0.8f * ((a0.x + a1.x) + (a2.x + a3.x));
            r.y = 0.2f * self.y + 0.8f * ((a0.y + a1.y) + (a2.y + a3.y));
            r.z = 0.2f * self.z + 0.8f * ((a0.z + a1.z) + (a2.z + a3.z));
            r.w = 0.2f * self.w + 0.8f * ((a0.w + a1.w) + (a2.w + a3.w));
            storeh4(emb_b + (size_t)row * DIM + t * 4, r);
        }
        // acc1 += e1 at sampled slots
        for (int i = gid; i < NSAMP * 16; i += gsz) {
            int s  = i >> 4;
            int tt = i & 15;
            int node = (s < NB) ? users[s] : (NUM_USERS + items[s - NB]);
            float4 v = loadh4(emb_a + (size_t)node * DIM + tt * 4);
            float4* ap = (float4*)(acc_small + (size_t)s * DIM + tt * 4);
            float4 a = *ap;
            a.x += v.x; a.y += v.y; a.z += v.z; a.w += v.w;
            *ap = a;
        }
    }

    __threadfence();
    grid.sync();

    // ================= phase C: layer-3 slot-form + fused dot ==============
    if (blockIdx.x < NSAMP / 32) {                 // 256 blocks x 32 groups = 8192
        const int G    = (int)blockIdx.x * 32 + group;
        const int w    = G >> 1;
        const int role = G & 1;                    // 0 = user slot, 1 = item slot
        const int s    = role ? (NB + w) : w;
        const int node = role ? (NUM_USERS + items[w]) : users[w];

        int cnt = counts[node];
        cnt = cnt < ELL_W ? cnt : ELL_W;
        const int2* ep = ell + (size_t)node * ELL_W;
        float4 a0 = {0,0,0,0}, a1 = {0,0,0,0}, a2 = {0,0,0,0}, a3 = {0,0,0,0};
        int j = 0;
        for (; j + 4 <= cnt; j += 4) {
            int4 cv0 = *(const int4*)(ep + j);
            int4 cv1 = *(const int4*)(ep + j + 2);
            float4 x0 = loadh4(emb_b + (size_t)cv0.x * DIM + t * 4);
            float4 x1 = loadh4(emb_b + (size_t)cv0.z * DIM + t * 4);
            float4 x2 = loadh4(emb_b + (size_t)cv1.x * DIM + t * 4);
            float4 x3 = loadh4(emb_b + (size_t)cv1.z * DIM + t * 4);
            a0 = f4fma(__int_as_float(cv0.y), x0, a0);
            a1 = f4fma(__int_as_float(cv0.w), x1, a1);
            a2 = f4fma(__int_as_float(cv1.y), x2, a2);
            a3 = f4fma(__int_as_float(cv1.w), x3, a3);
        }
        for (; j + 2 <= cnt; j += 2) {
            int4 cv = *(const int4*)(ep + j);
            float4 x0 = loadh4(emb_b + (size_t)cv.x * DIM + t * 4);
            float4 x1 = loadh4(emb_b + (size_t)cv.z * DIM + t * 4);
            a0 = f4fma(__int_as_float(cv.y), x0, a0);
            a1 = f4fma(__int_as_float(cv.w), x1, a1);
        }
        if (j < cnt) {
            int2 cv = ep[j];
            float4 xv = loadh4(emb_b + (size_t)cv.x * DIM + t * 4);
            a0 = f4fma(__int_as_float(cv.y), xv, a0);
        }
        int novf = *ovf_cnt;
        if (novf > 0) {
            novf = novf < OVF_CAP ? novf : OVF_CAP;
            for (int k = 0; k < novf; ++k) {
                int4 o = ovf[k];
                if (o.x == node) {
                    float4 xv = loadh4(emb_b + (size_t)o.y * DIM + t * 4);
                    a0 = f4fma(__int_as_float(o.z), xv, a0);
                }
            }
        }
        float4 self = loadh4(emb_b + (size_t)node * DIM + t * 4);
        float4 a = *(float4*)(acc_small + (size_t)s * DIM + t * 4);  // e0 + e1
        a.x += 1.2f * self.x + 0.8f * ((a0.x + a1.x) + (a2.x + a3.x));
        a.y += 1.2f * self.y + 0.8f * ((a0.y + a1.y) + (a2.y + a3.y));
        a.z += 1.2f * self.z + 0.8f * ((a0.z + a1.z) + (a2.z + a3.z));
        a.w += 1.2f * self.w + 0.8f * ((a0.w + a1.w) + (a2.w + a3.w));
        // fused dot: partner group is lane^16 within the same wave
        float4 b;
        b.x = __shfl_xor(a.x, 16, 64);
        b.y = __shfl_xor(a.y, 16, 64);
        b.z = __shfl_xor(a.z, 16, 64);
        b.w = __shfl_xor(a.w, 16, 64);
        float p = a.x * b.x + a.y * b.y + a.z * b.z + a.w * b.w;
        p += __shfl_xor(p, 1, 64);
        p += __shfl_xor(p, 2, 64);
        p += __shfl_xor(p, 4, 64);
        p += __shfl_xor(p, 8, 64);
        if (role == 0 && t == 0) out[w] = p * 0.0625f;   // (u/4)·(i/4)
    }
}

// ---------------------------------------------------------------------------
extern "C" void kernel_launch(void* const* d_in, const int* in_sizes, int n_in,
                              void* d_out, int out_size, void* d_ws, size_t ws_size,
                              hipStream_t stream) {
    const int*   users = (const int*)  d_in[0];
    const int*   items = (const int*)  d_in[1];
    const int*   erow  = (const int*)  d_in[2];
    const int*   ecol  = (const int*)  d_in[3];
    const float* evalv = (const float*)d_in[4];
    const float* ue    = (const float*)d_in[5];
    const float* ie    = (const float*)d_in[6];
    float* out = (float*)d_out;

    // workspace layout (~119 MB)
    __half* xh        = (__half*)d_ws;                      // 19.2 MB
    __half* emb_a     = xh + ND;                            // 19.2 MB
    __half* emb_b     = emb_a + ND;                         // 19.2 MB
    float*  acc_small = (float*)(emb_b + ND);               // 2 MB
    int2*   barr      = (int2*)(acc_small + NSAMP * DIM);   // 11.0 MB
    int2*   ell       = barr + (size_t)NBKT * BCAP;         // 28.8 MB
    int*    counts    = (int*)(ell + (size_t)NROWS_PAD * ELL_W); // 0.6 MB
    int*    gtails    = counts + NROWS_PAD;                 // NBKT
    int*    ovf_cnt   = gtails + NBKT;                      // 1
    int4*   ovf       = (int4*)(((uintptr_t)(ovf_cnt + 1) + 15) & ~(uintptr_t)15);
    unsigned char* mask3 = (unsigned char*)(ovf + OVF_CAP); // N_NODES
    unsigned char* mask2 = mask3 + N_NODES;                 // N_NODES

    // zero gtails | ovf_cnt | ovf | mask3 | mask2 (contiguous, ~310 KB)
    size_t zbytes = (size_t)((mask2 + N_NODES) - (unsigned char*)gtails);
    hipMemsetAsync(gtails, 0, zbytes, stream);

    k1_kernel<<<K1_EDGE_BLOCKS + K1_MARK_BLOCKS + K1_CVT_BLOCKS, K1_THREADS, 0, stream>>>(
        erow, ecol, evalv, users, items, ue, ie,
        gtails, barr, ovf, ovf_cnt, mask3, xh);

    {
        const int*   a_erow  = erow;
        const int*   a_ecol  = ecol;
        const int*   a_gt    = gtails;
        const int2*  a_barr  = barr;
        const __half* a_xh   = xh;
        const float* a_ue    = ue;
        const float* a_ie    = ie;
        int*         a_cnts  = counts;
        int2*        a_ell   = ell;
        int4*        a_ovf   = ovf;
        int*         a_ovfc  = ovf_cnt;
        const unsigned char* a_m3 = mask3;
        unsigned char* a_m2  = mask2;
        const int*   a_users = users;
        const int*   a_items = items;
        float*       a_acc   = acc_small;
        __half*      a_ea    = emb_a;
        __half*      a_eb    = emb_b;
        float*       a_out   = out;
        void* margs[] = { &a_erow, &a_ecol, &a_gt, &a_barr, &a_xh, &a_ue, &a_ie,
                          &a_cnts, &a_ell, &a_ovf, &a_ovfc, &a_m3, &a_m2,
                          &a_users, &a_items, &a_acc, &a_ea, &a_eb, &a_out };
        hipLaunchCooperativeKernel((void*)mega_kernel,
                                   dim3(MEGA_BLOCKS), dim3(MEGA_THREADS),
                                   margs, 0, stream);
    }
}

// Round 3
// 182.892 us; speedup vs baseline: 2.9265x; 2.9265x over previous
//
#include <hip/hip_runtime.h>
#include <hip/hip_fp16.h>
#include <stdint.h>
#include <string.h>

// LightGCN propagation — R17: revert to R15 split-kernel structure
// (mega-fusion regressed 2.9x: LDS-pinned occupancy + grid.sync serialization),
// plus: sp3+dot fused via paired 16-lane groups (shfl_xor(16)), and a wider
// cvt ride-along in k1 (128 -> 208 blocks).
//  K1: single-round LDS-staged counting sort (293 edge blocks, SCAP=13)
//      + parallel flat writeout + mark + cvt ride-alongs.
//  s1: 512 thr/block: ELL build (LDS) -> cnt-pruned writeout -> layer-1 spmm
//      from LDS; acc0 + expand + copy ride-alongs.
//  spmm2: global ELL (mask2 rows), fp16 gathers + acc1 ride-along.
//  sp3dot: slot-form layer 3 + fused batched dot (user/item pair adjacent
//      16-lane groups of one wave).

#define NUM_USERS 100000
#define NUM_ITEMS 50000
#define N_NODES   150000
#define DIM       64
#define N_EDGES   1200000
#define ND        (N_NODES * DIM)
#define NB        4096
#define NSAMP     (2 * NB)

#define ELL_W     24
#define NBKT      640               // buckets
#define RPB       235               // rows per bucket (640*235 = 150400)
#define NROWS_PAD (NBKT * RPB)
#define BCAP      2176              // records per bucket array (mean 1875, +7s)
#define SCAP      13                // K1 LDS staging records per bucket
#define OVF_CAP   512

#define K1_THREADS     1024
#define K1_EDGE_BLOCKS 293          // 293*1024*4 = 1,200,128 >= N_EDGES
#define K1_MARK_BLOCKS 8            // 8*1024 = 8192 = NSAMP
#define K1_CVT_BLOCKS  208          // wider cvt tail (grid 509 <= 512 slots)

#define S1_THREADS     512
#define S1_ACC_BLOCKS  256          // 32 slots/block * 256 = 8192
#define S1_EXP_BLOCKS  1024
#define S1_CPY_BLOCKS  293          // 293*512 >= N_NODES

#define SPMM_BLOCKS    9375         // 16 rows/block
#define ACC_BLOCKS     512          // 16 slots/block
#define SP3_BLOCKS     512          // 16 groups/block over 8192 slot-groups

// ---- fp16 pack/unpack helpers (compute in fp32) ---------------------------
__device__ __forceinline__ int h2i(__half2 h) { int r; memcpy(&r, &h, 4); return r; }
__device__ __forceinline__ __half2 i2h(int i) { __half2 h; memcpy(&h, &i, 4); return h; }

__device__ __forceinline__ float4 loadh4(const __half* p) {
    int2 v = *(const int2*)p;
    float2 a = __half22float2(i2h(v.x));
    float2 b = __half22float2(i2h(v.y));
    return make_float4(a.x, a.y, b.x, b.y);
}
__device__ __forceinline__ void storeh4(__half* p, float4 v) {
    int2 o;
    o.x = h2i(__floats2half2_rn(v.x, v.y));
    o.y = h2i(__floats2half2_rn(v.z, v.w));
    *(int2*)p = o;
}
__device__ __forceinline__ float4 f4fma(float v, float4 x, float4 a) {
    a.x += v * x.x; a.y += v * x.y; a.z += v * x.z; a.w += v * x.w;
    return a;
}

// ---------------------------------------------------------------------------
// K1: single-round LDS-staged counting sort + parallel writeout
//     + mark + cvt ride-alongs
// ---------------------------------------------------------------------------
__global__ __launch_bounds__(K1_THREADS)
void k1_kernel(const int* __restrict__ erow,
               const int* __restrict__ ecol,
               const float* __restrict__ evalv,
               const int* __restrict__ users,
               const int* __restrict__ items,
               const float* __restrict__ ue,
               const float* __restrict__ ie,
               int* __restrict__ gtails,
               int2* __restrict__ barr,
               int4* __restrict__ ovf,
               int* __restrict__ ovf_cnt,
               unsigned char* __restrict__ mask3,
               __half* __restrict__ xh) {
    __shared__ int2 stage[NBKT * SCAP];   // 66.6 KB
    __shared__ int  scnt[NBKT];           // 2.5 KB
    __shared__ int  gpos[NBKT];           // 2.5 KB
    if (blockIdx.x < K1_EDGE_BLOCKS) {
        for (int k = threadIdx.x; k < NBKT; k += K1_THREADS) scnt[k] = 0;
        __syncthreads();
        int base = ((int)blockIdx.x * K1_THREADS + (int)threadIdx.x) * 4;
        if (base < N_EDGES) {            // N_EDGES % 4 == 0 -> all 4 valid
            int4   r4 = *(const int4*)(erow + base);
            int4   c4 = *(const int4*)(ecol + base);
            float4 v4 = *(const float4*)(evalv + base);
            int   rr[4] = {r4.x, r4.y, r4.z, r4.w};
            int   cc[4] = {c4.x, c4.y, c4.z, c4.w};
            float vv[4] = {v4.x, v4.y, v4.z, v4.w};
            #pragma unroll
            for (int u = 0; u < 4; ++u) {
                int b    = rr[u] / RPB;
                int rloc = rr[u] - b * RPB;
                int2 rec = make_int2(cc[u] | (rloc << 18), __float_as_int(vv[u]));
                int s = atomicAdd(&scnt[b], 1);
                if (s < SCAP) {
                    stage[b * SCAP + s] = rec;
                } else {
                    // rare: spill straight to global
                    int gp = atomicAdd(&gtails[b], 1);
                    if (gp < BCAP) barr[(size_t)b * BCAP + gp] = rec;
                    else { int q = atomicAdd(ovf_cnt, 1);
                           if (q < OVF_CAP)
                               ovf[q] = make_int4(rr[u], cc[u], __float_as_int(vv[u]), 0); }
                }
            }
        }
        __syncthreads();
        // grab per-bucket global ranges (one atomic per bucket)
        for (int b = threadIdx.x; b < NBKT; b += K1_THREADS) {
            int c = scnt[b];
            c = c < SCAP ? c : SCAP;     // clamp: spilled records already placed
            scnt[b] = c;
            gpos[b] = (c > 0) ? atomicAdd(&gtails[b], c) : 0;
        }
        __syncthreads();
        // flat parallel writeout over (bucket, record) pairs — all 1024 threads
        for (int idx = threadIdx.x; idx < NBKT * SCAP; idx += K1_THREADS) {
            int b = idx / SCAP;
            int i = idx - b * SCAP;
            if (i < scnt[b]) {
                int2 rc = stage[idx];
                int gp = gpos[b] + i;
                if (gp < BCAP) barr[(size_t)b * BCAP + gp] = rc;
                else { int q = atomicAdd(ovf_cnt, 1);
                       if (q < OVF_CAP)
                           ovf[q] = make_int4(b * RPB + (rc.x >> 18),
                                              rc.x & 0x3FFFF, rc.y, 0); }
            }
        }
    } else if (blockIdx.x < K1_EDGE_BLOCKS + K1_MARK_BLOCKS) {
        int i = ((int)blockIdx.x - K1_EDGE_BLOCKS) * K1_THREADS + (int)threadIdx.x;
        if (i < NB)         mask3[users[i]] = 1;
        else if (i < NSAMP) mask3[NUM_USERS + items[i - NB]] = 1;
    } else {
        const int n4  = ND / 4;
        const int nu4 = NUM_USERS * DIM / 4;
        int i = ((int)blockIdx.x - K1_EDGE_BLOCKS - K1_MARK_BLOCKS) * K1_THREADS
                + (int)threadIdx.x;
        const int stride = K1_CVT_BLOCKS * K1_THREADS;
        int2* xh4 = (int2*)xh;
        for (; i < n4; i += stride) {
            float4 v = (i < nu4) ? ((const float4*)ue)[i]
                                 : ((const float4*)ie)[i - nu4];
            int2 o;
            o.x = h2i(__floats2half2_rn(v.x, v.y));
            o.y = h2i(__floats2half2_rn(v.z, v.w));
            xh4[i] = o;
        }
    }
}

// ---------------------------------------------------------------------------
// s1 (512 threads): ELL build (LDS) + cnt-pruned writeout + layer-1 spmm
//     from LDS + acc0 + mask expand + mask copy ride-alongs
// ---------------------------------------------------------------------------
__global__ __launch_bounds__(S1_THREADS)
void s1_kernel(const int* __restrict__ erow,
               const int* __restrict__ ecol,
               const int* __restrict__ gtails,
               const int2* __restrict__ barr,
               const __half* __restrict__ xh,
               const float* __restrict__ ue,
               const float* __restrict__ ie,
               int* __restrict__ counts,
               int2* __restrict__ ell,
               int4* __restrict__ ovf,
               int* __restrict__ ovf_cnt,
               const unsigned char* __restrict__ mask3,
               unsigned char* __restrict__ mask2,
               const int* __restrict__ users,
               const int* __restrict__ items,
               float* __restrict__ acc_small,
               __half* __restrict__ emb_out) {
    __shared__ __align__(16) int2 lell[RPB * ELL_W];   // 45.1 KB
    __shared__ int lcnt[RPB];
    const int group = threadIdx.x >> 4;   // 0..31
    const int t     = threadIdx.x & 15;

    if (blockIdx.x < NBKT) {
        const int bkt   = blockIdx.x;
        const int rbase = bkt * RPB;
        // ---- phase 1: build LDS ELL from sorted records ----
        for (int k = threadIdx.x; k < RPB; k += S1_THREADS) lcnt[k] = 0;
        __syncthreads();
        int n = gtails[bkt];
        n = n < BCAP ? n : BCAP;
        for (int e = threadIdx.x; e < n; e += S1_THREADS) {
            int2 rec = barr[(size_t)bkt * BCAP + e];
            int col  = rec.x & 0x3FFFF;
            int rloc = rec.x >> 18;
            int slot = atomicAdd(&lcnt[rloc], 1);
            if (slot < ELL_W)
                lell[rloc * ELL_W + slot] = make_int2(col, rec.y);
            else { int q = atomicAdd(ovf_cnt, 1);
                   if (q < OVF_CAP) ovf[q] = make_int4(rbase + rloc, col, rec.y, 0); }
        }
        __syncthreads();
        // ---- phase 2: cnt-pruned writeout (rows are 192B line-aligned) ----
        {
            int4* g4 = (int4*)(ell + (size_t)rbase * ELL_W);
            const int4* l4 = (const int4*)lell;
            const int PPR = ELL_W / 2;   // 12 int4 pairs per row
            for (int idx = threadIdx.x; idx < RPB * PPR; idx += S1_THREADS) {
                int row = idx / PPR;
                int pr  = idx - row * PPR;
                int c = lcnt[row]; c = c < ELL_W ? c : ELL_W;
                if (pr * 2 < c) g4[idx] = l4[idx];
            }
            for (int k = threadIdx.x; k < RPB; k += S1_THREADS)
                counts[rbase + k] = lcnt[k];
        }
        // ---- phase 3: layer-1 spmm reading ELL from LDS ----
        int novf = *ovf_cnt;
        novf = novf < OVF_CAP ? novf : OVF_CAP;
        for (int k = 0; k < 8; ++k) {                 // 32 groups x 8 = 256 >= 235
            int rloc = group + 32 * k;
            if (rloc >= RPB) break;
            int row = rbase + rloc;
            if (row >= N_NODES) continue;
            int cnt = lcnt[rloc];
            cnt = cnt < ELL_W ? cnt : ELL_W;
            const int2* ep = &lell[rloc * ELL_W];
            float4 a0 = {0,0,0,0}, a1 = {0,0,0,0}, a2 = {0,0,0,0}, a3 = {0,0,0,0};
            int j = 0;
            for (; j + 4 <= cnt; j += 4) {
                int4 cv0 = *(const int4*)(ep + j);
                int4 cv1 = *(const int4*)(ep + j + 2);
                float4 x0 = loadh4(xh + (size_t)cv0.x * DIM + t * 4);
                float4 x1 = loadh4(xh + (size_t)cv0.z * DIM + t * 4);
                float4 x2 = loadh4(xh + (size_t)cv1.x * DIM + t * 4);
                float4 x3 = loadh4(xh + (size_t)cv1.z * DIM + t * 4);
                a0 = f4fma(__int_as_float(cv0.y), x0, a0);
                a1 = f4fma(__int_as_float(cv0.w), x1, a1);
                a2 = f4fma(__int_as_float(cv1.y), x2, a2);
                a3 = f4fma(__int_as_float(cv1.w), x3, a3);
            }
            for (; j + 2 <= cnt; j += 2) {
                int4 cv = *(const int4*)(ep + j);
                float4 x0 = loadh4(xh + (size_t)cv.x * DIM + t * 4);
                float4 x1 = loadh4(xh + (size_t)cv.z * DIM + t * 4);
                a0 = f4fma(__int_as_float(cv.y), x0, a0);
                a1 = f4fma(__int_as_float(cv.w), x1, a1);
            }
            if (j < cnt) {
                int2 cv = ep[j];
                float4 xv = loadh4(xh + (size_t)cv.x * DIM + t * 4);
                a0 = f4fma(__int_as_float(cv.y), xv, a0);
            }
            for (int q = 0; q < novf; ++q) {
                int4 o = ovf[q];
                if (o.x == row) {
                    float4 xv = loadh4(xh + (size_t)o.y * DIM + t * 4);
                    a0 = f4fma(__int_as_float(o.z), xv, a0);
                }
            }
            float4 self = loadh4(xh + (size_t)row * DIM + t * 4);
            float4 r;
            r.x = 0.2f * self.x + 0.8f * ((a0.x + a1.x) + (a2.x + a3.x));
            r.y = 0.2f * self.y + 0.8f * ((a0.y + a1.y) + (a2.y + a3.y));
            r.z = 0.2f * self.z + 0.8f * ((a0.z + a1.z) + (a2.z + a3.z));
            r.w = 0.2f * self.w + 0.8f * ((a0.w + a1.w) + (a2.w + a3.w));
            storeh4(emb_out + (size_t)row * DIM + t * 4, r);
        }
    } else if (blockIdx.x < NBKT + S1_ACC_BLOCKS) {
        // acc0: store layer-0 contribution from the fp32 tables (32 slots/blk)
        const int s = ((int)blockIdx.x - NBKT) * 32 + group;   // < 8192
        const int node = (s < NB) ? users[s] : (NUM_USERS + items[s - NB]);
        const float* p = (node < NUM_USERS) ? ue + (size_t)node * DIM
                                            : ie + (size_t)(node - NUM_USERS) * DIM;
        *(float4*)(acc_small + (size_t)s * DIM + t * 4) = *(const float4*)(p + t * 4);
    } else if (blockIdx.x < NBKT + S1_ACC_BLOCKS + S1_EXP_BLOCKS) {
        int i = ((int)blockIdx.x - NBKT - S1_ACC_BLOCKS) * S1_THREADS
                + (int)threadIdx.x;
        const int stride = S1_EXP_BLOCKS * S1_THREADS;
        for (; i < N_EDGES; i += stride)
            if (mask3[erow[i]]) mask2[ecol[i]] = 1;
    } else {
        int i = ((int)blockIdx.x - NBKT - S1_ACC_BLOCKS - S1_EXP_BLOCKS) * S1_THREADS
                + (int)threadIdx.x;
        if (i < N_NODES && mask3[i]) mask2[i] = 1;
    }
}

// ---------------------------------------------------------------------------
// spmm2 (layer 2): global ELL, masked, fp16 gathers + acc1 ride-along
// ---------------------------------------------------------------------------
__global__ void spmm_kernel(const int* __restrict__ counts,
                            const int2* __restrict__ ell,
                            const __half* __restrict__ xsrc,
                            const unsigned char* __restrict__ mask,
                            const int* __restrict__ ovf_cnt,
                            const int4* __restrict__ ovf,
                            const int* __restrict__ users,
                            const int* __restrict__ items,
                            float* __restrict__ acc_small,
                            __half* __restrict__ xout) {
    const int wid  = threadIdx.x >> 6;
    const int lane = threadIdx.x & 63;
    const int g    = lane >> 4;
    const int t    = lane & 15;

    if (blockIdx.x < SPMM_BLOCKS) {
        const int row = blockIdx.x * 16 + wid * 4 + g;
        bool active = mask[row] != 0;
        int cnt = 0;
        if (active) {
            cnt = counts[row];
            cnt = cnt < ELL_W ? cnt : ELL_W;
        }
        const int2* ep = ell + (size_t)row * ELL_W;
        float4 a0 = {0,0,0,0}, a1 = {0,0,0,0}, a2 = {0,0,0,0}, a3 = {0,0,0,0};
        int j = 0;
        for (; j + 4 <= cnt; j += 4) {
            int4 cv0 = *(const int4*)(ep + j);
            int4 cv1 = *(const int4*)(ep + j + 2);
            float4 x0 = loadh4(xsrc + (size_t)cv0.x * DIM + t * 4);
            float4 x1 = loadh4(xsrc + (size_t)cv0.z * DIM + t * 4);
            float4 x2 = loadh4(xsrc + (size_t)cv1.x * DIM + t * 4);
            float4 x3 = loadh4(xsrc + (size_t)cv1.z * DIM + t * 4);
            a0 = f4fma(__int_as_float(cv0.y), x0, a0);
            a1 = f4fma(__int_as_float(cv0.w), x1, a1);
            a2 = f4fma(__int_as_float(cv1.y), x2, a2);
            a3 = f4fma(__int_as_float(cv1.w), x3, a3);
        }
        for (; j + 2 <= cnt; j += 2) {
            int4 cv = *(const int4*)(ep + j);
            float4 x0 = loadh4(xsrc + (size_t)cv.x * DIM + t * 4);
            float4 x1 = loadh4(xsrc + (size_t)cv.z * DIM + t * 4);
            a0 = f4fma(__int_as_float(cv.y), x0, a0);
            a1 = f4fma(__int_as_float(cv.w), x1, a1);
        }
        if (j < cnt) {
            int2 cv = ep[j];
            float4 xv = loadh4(xsrc + (size_t)cv.x * DIM + t * 4);
            a0 = f4fma(__int_as_float(cv.y), xv, a0);
        }
        int novf = *ovf_cnt;
        if (novf > 0) {
            novf = novf < OVF_CAP ? novf : OVF_CAP;
            for (int k = 0; k < novf; ++k) {
                int4 o = ovf[k];
                if (active && o.x == row) {
                    float4 xv = loadh4(xsrc + (size_t)o.y * DIM + t * 4);
                    a0 = f4fma(__int_as_float(o.z), xv, a0);
                }
            }
        }
        if (active) {
            float4 self = loadh4(xsrc + (size_t)row * DIM + t * 4);
            float4 r;
            r.x = 0.2f * self.x + 0.8f * ((a0.x + a1.x) + (a2.x + a3.x));
            r.y = 0.2f * self.y + 0.8f * ((a0.y + a1.y) + (a2.y + a3.y));
            r.z = 0.2f * self.z + 0.8f * ((a0.z + a1.z) + (a2.z + a3.z));
            r.w = 0.2f * self.w + 0.8f * ((a0.w + a1.w) + (a2.w + a3.w));
            storeh4(xout + (size_t)row * DIM + t * 4, r);
        }
    } else {
        // acc1 += e1 at sampled slots (xsrc = emb_a)
        const int s = (blockIdx.x - SPMM_BLOCKS) * 16 + wid * 4 + g;
        const int node = (s < NB) ? users[s] : (NUM_USERS + items[s - NB]);
        float4 v = loadh4(xsrc + (size_t)node * DIM + t * 4);
        float4* ap = (float4*)(acc_small + (size_t)s * DIM + t * 4);
        float4 a = *ap;
        a.x += v.x; a.y += v.y; a.z += v.z; a.w += v.w;
        *ap = a;
    }
}

// ---------------------------------------------------------------------------
// sp3dot: slot-form layer 3 + fused batched dot.
//   Pair (user slot w, item slot NB+w) sit in adjacent 16-lane groups of the
//   same wave -> partner acc via shfl_xor(16), reduce via shfl_xor(1,2,4,8).
// ---------------------------------------------------------------------------
__global__ void sp3dot_kernel(const int* __restrict__ counts,
                              const int2* __restrict__ ell,
                              const __half* __restrict__ emb2,
                              const int* __restrict__ ovf_cnt,
                              const int4* __restrict__ ovf,
                              const int* __restrict__ users,
                              const int* __restrict__ items,
                              const float* __restrict__ acc_small,
                              float* __restrict__ out) {
    const int wid  = threadIdx.x >> 6;
    const int lane = threadIdx.x & 63;
    const int g    = lane >> 4;
    const int t    = lane & 15;
    const int G    = blockIdx.x * 16 + wid * 4 + g;       // < 8192
    if (G >= NSAMP) return;
    const int w    = G >> 1;
    const int role = G & 1;                    // 0 = user slot, 1 = item slot
    const int s    = role ? (NB + w) : w;
    const int node = role ? (NUM_USERS + items[w]) : users[w];

    int cnt = counts[node];
    cnt = cnt < ELL_W ? cnt : ELL_W;
    const int2* ep = ell + (size_t)node * ELL_W;
    float4 a0 = {0,0,0,0}, a1 = {0,0,0,0}, a2 = {0,0,0,0}, a3 = {0,0,0,0};
    int j = 0;
    for (; j + 4 <= cnt; j += 4) {
        int4 cv0 = *(const int4*)(ep + j);
        int4 cv1 = *(const int4*)(ep + j + 2);
        float4 x0 = loadh4(emb2 + (size_t)cv0.x * DIM + t * 4);
        float4 x1 = loadh4(emb2 + (size_t)cv0.z * DIM + t * 4);
        float4 x2 = loadh4(emb2 + (size_t)cv1.x * DIM + t * 4);
        float4 x3 = loadh4(emb2 + (size_t)cv1.z * DIM + t * 4);
        a0 = f4fma(__int_as_float(cv0.y), x0, a0);
        a1 = f4fma(__int_as_float(cv0.w), x1, a1);
        a2 = f4fma(__int_as_float(cv1.y), x2, a2);
        a3 = f4fma(__int_as_float(cv1.w), x3, a3);
    }
    for (; j + 2 <= cnt; j += 2) {
        int4 cv = *(const int4*)(ep + j);
        float4 x0 = loadh4(emb2 + (size_t)cv.x * DIM + t * 4);
        float4 x1 = loadh4(emb2 + (size_t)cv.z * DIM + t * 4);
        a0 = f4fma(__int_as_float(cv.y), x0, a0);
        a1 = f4fma(__int_as_float(cv.w), x1, a1);
    }
    if (j < cnt) {
        int2 cv = ep[j];
        float4 xv = loadh4(emb2 + (size_t)cv.x * DIM + t * 4);
        a0 = f4fma(__int_as_float(cv.y), xv, a0);
    }
    int novf = *ovf_cnt;
    if (novf > 0) {
        novf = novf < OVF_CAP ? novf : OVF_CAP;
        for (int k = 0; k < novf; ++k) {
            int4 o = ovf[k];
            if (o.x == node) {
                float4 xv = loadh4(emb2 + (size_t)o.y * DIM + t * 4);
                a0 = f4fma(__int_as_float(o.z), xv, a0);
            }
        }
    }
    float4 self = loadh4(emb2 + (size_t)node * DIM + t * 4);
    float4 a = *(const float4*)(acc_small + (size_t)s * DIM + t * 4);  // e0+e1
    a.x += 1.2f * self.x + 0.8f * ((a0.x + a1.x) + (a2.x + a3.x));
    a.y += 1.2f * self.y + 0.8f * ((a0.y + a1.y) + (a2.y + a3.y));
    a.z += 1.2f * self.z + 0.8f * ((a0.z + a1.z) + (a2.z + a3.z));
    a.w += 1.2f * self.w + 0.8f * ((a0.w + a1.w) + (a2.w + a3.w));
    // fused dot: partner group is lane^16 within the same wave
    float4 b;
    b.x = __shfl_xor(a.x, 16, 64);
    b.y = __shfl_xor(a.y, 16, 64);
    b.z = __shfl_xor(a.z, 16, 64);
    b.w = __shfl_xor(a.w, 16, 64);
    float p = a.x * b.x + a.y * b.y + a.z * b.z + a.w * b.w;
    p += __shfl_xor(p, 1, 64);
    p += __shfl_xor(p, 2, 64);
    p += __shfl_xor(p, 4, 64);
    p += __shfl_xor(p, 8, 64);
    if (role == 0 && t == 0) out[w] = p * 0.0625f;   // (u/4)·(i/4)
}

// ---------------------------------------------------------------------------
extern "C" void kernel_launch(void* const* d_in, const int* in_sizes, int n_in,
                              void* d_out, int out_size, void* d_ws, size_t ws_size,
                              hipStream_t stream) {
    const int*   users = (const int*)  d_in[0];
    const int*   items = (const int*)  d_in[1];
    const int*   erow  = (const int*)  d_in[2];
    const int*   ecol  = (const int*)  d_in[3];
    const float* evalv = (const float*)d_in[4];
    const float* ue    = (const float*)d_in[5];
    const float* ie    = (const float*)d_in[6];
    float* out = (float*)d_out;

    // workspace layout (~101 MB)
    __half* xh        = (__half*)d_ws;                      // 19.2 MB
    __half* emb_a     = xh + ND;                            // 19.2 MB
    __half* emb_b     = emb_a + ND;                         // 19.2 MB
    float*  acc_small = (float*)(emb_b + ND);               // 2 MB
    int2*   barr      = (int2*)(acc_small + NSAMP * DIM);   // 11.1 MB
    int2*   ell       = barr + (size_t)NBKT * BCAP;         // 28.9 MB
    int*    counts    = (int*)(ell + (size_t)NROWS_PAD * ELL_W); // 0.6 MB
    int*    gtails    = counts + NROWS_PAD;                 // NBKT
    int*    ovf_cnt   = gtails + NBKT;                      // 1
    int4*   ovf       = (int4*)(((uintptr_t)(ovf_cnt + 1) + 15) & ~(uintptr_t)15);
    unsigned char* mask3 = (unsigned char*)(ovf + OVF_CAP); // N_NODES
    unsigned char* mask2 = mask3 + N_NODES;                 // N_NODES

    // zero gtails | ovf_cnt | ovf | mask3 | mask2 (contiguous, ~310 KB)
    size_t zbytes = (size_t)((mask2 + N_NODES) - (unsigned char*)gtails);
    hipMemsetAsync(gtails, 0, zbytes, stream);

    k1_kernel<<<K1_EDGE_BLOCKS + K1_MARK_BLOCKS + K1_CVT_BLOCKS, K1_THREADS, 0, stream>>>(
        erow, ecol, evalv, users, items, ue, ie,
        gtails, barr, ovf, ovf_cnt, mask3, xh);

    // s1: ELL build + pruned writeout + layer-1 spmm + acc0 + expand + copy
    s1_kernel<<<NBKT + S1_ACC_BLOCKS + S1_EXP_BLOCKS + S1_CPY_BLOCKS, S1_THREADS, 0, stream>>>(
        erow, ecol, gtails, barr, xh, ue, ie, counts, ell, ovf, ovf_cnt,
        mask3, mask2, users, items, acc_small, emb_a);

    // layer 2 (mask2) + acc1 (from emb_a)
    spmm_kernel<<<SPMM_BLOCKS + ACC_BLOCKS, 256, 0, stream>>>(
        counts, ell, emb_a, mask2, ovf_cnt, ovf,
        users, items, acc_small, emb_b);

    // layer 3 slot-form + fused dot
    sp3dot_kernel<<<SP3_BLOCKS, 256, 0, stream>>>(
        counts, ell, emb_b, ovf_cnt, ovf, users, items, acc_small, out);
}